// Round 7
// baseline (6525.083 us; speedup 1.0000x reference)
//
#include <hip/hip_runtime.h>

#define SEQn   1024
#define BATCHn 64
#define EMBn   256
#define HIDn   512
#define VOCn   512

#define NGRP 4                   /* independent batch groups of 16 rows      */
#define NL1g 16                  /* per group: 16 L1 blocks x 32 units       */
#define NL2g 16                  /* 16 L2 blocks x 32 units                  */
#define NFCg 16                  /* 16 FC blocks x 32 vocab cols             */
#define GBLK (NL1g + NL2g + NFCg)            /* 48 blocks per group          */
#define NBLK (NGRP * GBLK)                   /* 192 blocks, <= 256 CUs       */
#define NPHASE (SEQn + 2)        /* 1026 phases: skewed L1 / L2 / FC pipeline */
#define HS 8192                  /* f16 per h-slice: 16 rows x 512 = 16KB    */
#define NSLOT 8                  /* mod-8 timestep slots, single replica     */
#define THR_IGN (-1)             /* flags are >=0 -> always satisfied        */

using f16   = _Float16;
using half8 = __attribute__((ext_vector_type(8))) _Float16;
using f32x4 = __attribute__((ext_vector_type(4))) float;
using i32x4 = __attribute__((ext_vector_type(4))) int;

/* workspace layout (bytes) */
#define WS_FLG 0                 /* per group: 3 x 64B flag lines (L1,L2,FC) */
#define WS_H1  4096              /* [grp4][slot8][16KB] = 512KB              */
#define WS_H2  (WS_H1 + NGRP * NSLOT * HS * 2)
#define WS_P1  (WS_H2 + NGRP * NSLOT * HS * 2)   /* [512][2048] f16, 2MB     */

/* ---- h-slice layout (per group slot, 16 rows x 512 cols) ----
   idx = ks*512 + qq*128 + cc*8 + e   <->  row = cc, col = ks*32 + qq*8 + e */

__device__ __forceinline__ float sigm_(float v) { return 1.0f / (1.0f + __expf(-v)); }
__device__ __forceinline__ float tanh_(float v) { return 1.0f - 2.0f / (__expf(2.0f * v) + 1.0f); }

__device__ __forceinline__ void st_b128_sc1(f16* p, f32x4 v) {
  asm volatile("global_store_dwordx4 %0, %1, off sc1" :: "v"(p), "v"(v) : "memory");
}

/* device-scope loads + drain inside ONE asm block (compiler cannot hoist a
   consumer past the internal s_waitcnt). Each covers this wave's K-slices. */
__device__ __forceinline__ void ld2_sc1(const f16* base, half8 (&a)[2]) {
  f32x4 t0, t1;
  asm volatile(
    "global_load_dwordx4 %0, %2, off sc1\n\t"
    "global_load_dwordx4 %1, %2, off offset:1024 sc1\n\t"
    "s_waitcnt vmcnt(0)"
    : "=&v"(t0), "=&v"(t1) : "v"(base) : "memory");
  a[0] = __builtin_bit_cast(half8, t0);
  a[1] = __builtin_bit_cast(half8, t1);
}
__device__ __forceinline__ void ld4_sc1(const f16* base, half8 (&a)[4]) {
  f32x4 t0, t1, t2, t3;
  asm volatile(
    "global_load_dwordx4 %0, %4, off sc1\n\t"
    "global_load_dwordx4 %1, %4, off offset:1024 sc1\n\t"
    "global_load_dwordx4 %2, %4, off offset:2048 sc1\n\t"
    "global_load_dwordx4 %3, %4, off offset:3072 sc1\n\t"
    "s_waitcnt vmcnt(0)"
    : "=&v"(t0), "=&v"(t1), "=&v"(t2), "=&v"(t3) : "v"(base) : "memory");
  a[0] = __builtin_bit_cast(half8, t0);
  a[1] = __builtin_bit_cast(half8, t1);
  a[2] = __builtin_bit_cast(half8, t2);
  a[3] = __builtin_bit_cast(half8, t3);
}

/* ---- init: zero flags, seed slot-0 h1/h2 slices ---- */
__global__ void k_init(const float* __restrict__ h0, char* __restrict__ ws) {
  int i = blockIdx.x * 256 + threadIdx.x;          /* grid 128*256 = 32768 */
  f16* h1b = (f16*)(ws + WS_H1);
  f16* h2b = (f16*)(ws + WS_H2);
  int g = i >> 13;                     /* 4 groups x 8192 slice elements    */
  int off = i & (HS - 1);
  int ks = off >> 9, rem = off & 511;
  int qq = rem >> 7, cc = (rem >> 3) & 15, e = rem & 7;
  int row = g * 16 + cc, col = ks * 32 + qq * 8 + e;
  f16 v = (f16)h0[row * HIDn + col];
  int base = g * (NSLOT * HS);                     /* slot 0 */
  h1b[base + off] = v;
  h2b[base + off] = v;
  if (i < 256) ((int*)ws)[i] = 0;
}

/* ---- P1[v][g] = emb[v] . Wih1[g] + bih1[g] + bhh1[g]  (fp16) ---- */
__global__ void k_p1(const float* __restrict__ emb, const float* __restrict__ Wih1,
                     const float* __restrict__ bih1, const float* __restrict__ bhh1,
                     char* __restrict__ ws) {
  __shared__ float elds[32 * 256];
  int tid = threadIdx.x;
  int vb = blockIdx.x >> 5, gb = blockIdx.x & 31;  /* grid 512 */
  for (int i = tid; i < 32 * 256; i += 256) elds[i] = emb[vb * 32 * 256 + i];
  __syncthreads();
  int gl = tid & 63, vs = tid >> 6;
  int g = gb * 64 + gl;
  float bias = bih1[g] + bhh1[g];
  float acc[8];
#pragma unroll
  for (int r = 0; r < 8; ++r) acc[r] = bias;
  const float* wrow = Wih1 + g * EMBn;
#pragma unroll 4
  for (int e = 0; e < EMBn; ++e) {
    float w = wrow[e];
#pragma unroll
    for (int r = 0; r < 8; ++r) acc[r] += elds[(vs * 8 + r) * 256 + e] * w;
  }
  f16* P1 = (f16*)(ws + WS_P1);
#pragma unroll
  for (int r = 0; r < 8; ++r) P1[(vb * 32 + vs * 8 + r) * 2048 + g] = (f16)acc[r];
}

/* ---- persistent pipeline: per-wave decoupled poll + rotating store duty ---- */
__global__ void __launch_bounds__(512, 2)
k_lstm(const int* __restrict__ x, const float* __restrict__ c0,
       const float* __restrict__ Whh1,
       const float* __restrict__ Wih2, const float* __restrict__ Whh2,
       const float* __restrict__ bih2, const float* __restrict__ bhh2,
       const float* __restrict__ Wfc, const float* __restrict__ bfc,
       float* __restrict__ out, char* __restrict__ ws)
{
  __shared__ float part[8][16][132];   /* per-wave partial gates, padded    */
  __shared__ alignas(16) f16 hstage[16][32];

  const int bid = blockIdx.x, tid = threadIdx.x;
  const int lane = tid & 63, wv = tid >> 6;
  const int cc = lane & 15, qq = lane >> 4;
  const int group = bid / GBLK, role = bid % GBLK;

  f16* h1g = (f16*)(ws + WS_H1) + group * (NSLOT * HS);
  f16* h2g = (f16*)(ws + WS_H2) + group * (NSLOT * HS);
  const f16* P1 = (const f16*)(ws + WS_P1);
  /* class flag lines: [group][cls] = 16 ints each (one 64B line) */
  const int cls = (role < NL1g) ? 0 : (role < NL1g + NL2g) ? 1 : 2;
  const int owni = role & 15;          /* own flag dword within class line  */
  int* flagp = (int*)ws + (group << 6) + (cls << 4) + owni;

  half8 bfr[32];                       /* weight B-fragments, resident      */
  float cst = 0.f;                     /* epilogue cell state (1/thread)    */
  float biasr[4] = {0.f, 0.f, 0.f, 0.f};
  float bfcr = 0.f;
  float pgf[4] = {0.f, 0.f, 0.f, 0.f}; /* L1 pre-gathered P1 terms          */
  int j0 = 0;
  const int erow = tid >> 5, eu = tid & 31;   /* epilogue (row, unit/col)   */

  if (cls == 0) {
    /* L1: 32 units; tiles nt: gate = nt>>1, unit = (nt&1)*16 + cc */
    j0 = role * 32;
#pragma unroll
    for (int nt = 0; nt < 8; ++nt) {
      const float* wr = Whh1 + ((nt >> 1) * 512 + j0 + (nt & 1) * 16 + cc) * HIDn;
#pragma unroll
      for (int kk = 0; kk < 2; ++kk) {
        const float* s = wr + (wv * 2 + kk) * 32 + qq * 8;
        half8 hv;
#pragma unroll
        for (int j = 0; j < 8; ++j) hv[j] = (f16)s[j];
        bfr[nt * 2 + kk] = hv;
      }
    }
    cst = c0[(group * 16 + erow) * HIDn + j0 + eu];
    /* pre-gather P1 terms for phase 1 */
    {
      const f16* pr = P1 + (size_t)x[group * 16 + erow] * 2048 + j0 + eu;
#pragma unroll
      for (int g = 0; g < 4; ++g) pgf[g] = (float)pr[g * 512];
    }
  } else if (cls == 1) {
    /* L2: 32 units; waves: kh = wv>>2 (h1/h2 source), kq = wv&3 (K quarter) */
    j0 = (role - NL1g) * 32;
    const int kh = wv >> 2, kq = wv & 3;
    const float* W = kh ? Whh2 : Wih2;
#pragma unroll
    for (int nt = 0; nt < 8; ++nt) {
      const float* wr = W + ((nt >> 1) * 512 + j0 + (nt & 1) * 16 + cc) * HIDn;
#pragma unroll
      for (int kk = 0; kk < 4; ++kk) {
        const float* s = wr + (kq * 4 + kk) * 32 + qq * 8;
        half8 hv;
#pragma unroll
        for (int j = 0; j < 8; ++j) hv[j] = (f16)s[j];
        bfr[nt * 4 + kk] = hv;
      }
    }
#pragma unroll
    for (int g = 0; g < 4; ++g)
      biasr[g] = bih2[g * 512 + j0 + eu] + bhh2[g * 512 + j0 + eu];
    cst = c0[(group * 16 + erow) * HIDn + j0 + eu];
  } else {
    /* FC: 32 vocab cols */
    j0 = (role - NL1g - NL2g) * 32;
#pragma unroll
    for (int nt = 0; nt < 2; ++nt) {
      const float* wr = Wfc + (j0 + nt * 16 + cc) * HIDn;
#pragma unroll
      for (int kk = 0; kk < 2; ++kk) {
        const float* s = wr + (wv * 2 + kk) * 32 + qq * 8;
        half8 hv;
#pragma unroll
        for (int j = 0; j < 8; ++j) hv[j] = (f16)s[j];
        bfr[nt * 2 + kk] = hv;
      }
    }
    bfcr = bfc[j0 + eu];
  }
  const int ks0 = j0 >> 5;
  __syncthreads();

  for (int p = 1; p <= NPHASE; ++p) {
    const int act = (cls == 0) ? (p <= SEQn)
                  : (cls == 1) ? (p >= 2 && p <= SEQn + 1)
                               : (p >= 3);
    if (act) {
      if (cls == 0) {                  /* h1_p = f(h1_{p-1}, x_{p-1}) */
        const f16* hp = h1g + ((p - 1) & 7) * HS;
        half8 a[2];
        ld2_sc1(hp + wv * 1024 + lane * 8, a);
        /* own-block columns: substitute from LDS (global copy may be in
           flight from this block's duty wave) */
        if (p >= 2 && wv == (ks0 >> 1)) {
          half8 sub = *(const half8*)&hstage[cc][qq * 8];
          if ((ks0 & 1) == 0) a[0] = sub; else a[1] = sub;
        }
        f32x4 acc[8];
#pragma unroll
        for (int nt = 0; nt < 8; ++nt)
#pragma unroll
          for (int r = 0; r < 4; ++r) acc[nt][r] = 0.f;
#pragma unroll
        for (int kk = 0; kk < 2; ++kk)
#pragma unroll
          for (int nt = 0; nt < 8; ++nt)
            acc[nt] = __builtin_amdgcn_mfma_f32_16x16x32_f16(a[kk], bfr[nt * 2 + kk], acc[nt], 0, 0, 0);
#pragma unroll
        for (int nt = 0; nt < 8; ++nt)
#pragma unroll
          for (int r = 0; r < 4; ++r)
            part[wv][qq * 4 + r][nt * 16 + cc] = acc[nt][r];
      } else if (cls == 1) {           /* h2_{p-1} = f(h1_{p-1}, h2_{p-2}) */
        const int kh = wv >> 2, kq = wv & 3;
        const f16* src = kh ? h2g + ((p - 2) & 7) * HS
                            : h1g + ((p - 1) & 7) * HS;
        half8 a[4];
        ld4_sc1(src + kq * 2048 + lane * 8, a);
        if (p >= 3 && kh == 1 && kq == (ks0 >> 2)) {
          half8 sub = *(const half8*)&hstage[cc][qq * 8];
          int k3 = ks0 & 3;
          if (k3 == 0) a[0] = sub;
          else if (k3 == 1) a[1] = sub;
          else if (k3 == 2) a[2] = sub;
          else a[3] = sub;
        }
        f32x4 acc[8];
#pragma unroll
        for (int nt = 0; nt < 8; ++nt)
#pragma unroll
          for (int r = 0; r < 4; ++r) acc[nt][r] = 0.f;
#pragma unroll
        for (int kk = 0; kk < 4; ++kk)
#pragma unroll
          for (int nt = 0; nt < 8; ++nt)
            acc[nt] = __builtin_amdgcn_mfma_f32_16x16x32_f16(a[kk], bfr[nt * 4 + kk], acc[nt], 0, 0, 0);
#pragma unroll
        for (int nt = 0; nt < 8; ++nt)
#pragma unroll
          for (int r = 0; r < 4; ++r)
            part[wv][qq * 4 + r][nt * 16 + cc] = acc[nt][r];
      } else {                         /* out_{p-3} = h2_{p-2} @ WfcT + bfc */
        const f16* hp = h2g + ((p - 2) & 7) * HS;
        half8 a[2];
        ld2_sc1(hp + wv * 1024 + lane * 8, a);
        f32x4 acc[2];
#pragma unroll
        for (int nt = 0; nt < 2; ++nt)
#pragma unroll
          for (int r = 0; r < 4; ++r) acc[nt][r] = 0.f;
#pragma unroll
        for (int kk = 0; kk < 2; ++kk)
#pragma unroll
          for (int nt = 0; nt < 2; ++nt)
            acc[nt] = __builtin_amdgcn_mfma_f32_16x16x32_f16(a[kk], bfr[nt * 2 + kk], acc[nt], 0, 0, 0);
#pragma unroll
        for (int nt = 0; nt < 2; ++nt)
#pragma unroll
          for (int r = 0; r < 4; ++r)
            part[wv][qq * 4 + r][nt * 16 + cc] = acc[nt][r];
      }
    }
    __syncthreads();                   /* A: all part[] written             */
    if (act) {
      if (cls != 2) {
        float gs[4];
#pragma unroll
        for (int g = 0; g < 4; ++g) {
          float s = (cls == 0) ? pgf[g] : biasr[g];
#pragma unroll
          for (int kw = 0; kw < 8; ++kw) s += part[kw][erow][g * 32 + eu];
          gs[g] = s;
        }
        float cn = sigm_(gs[1]) * cst + sigm_(gs[0]) * tanh_(gs[2]);
        cst = cn;
        hstage[erow][eu] = (f16)(sigm_(gs[3]) * tanh_(cn));
      } else {
        float s = bfcr;
#pragma unroll
        for (int kw = 0; kw < 8; ++kw) s += part[kw][erow][eu];
        float* op = out + (size_t)(p - 3) * (BATCHn * VOCn)
                  + (group * 16 + erow) * VOCn + j0 + eu;
        __builtin_nontemporal_store(s, op);
      }
    }
    __syncthreads();                   /* B: hstage complete                */

    /* rotating store duty: one wave stores h_p, drains, publishes flag;
       the other 7 waves poll their own conditions and run ahead.        */
    const int duty = p & 7;
    if (act && cls != 2 && wv == duty) {
      f32x4 w = *(const f32x4*)&hstage[lane & 15][(lane >> 4) * 8];
      f16* ho = ((cls == 0) ? h1g + (p & 7) * HS : h2g + ((p - 1) & 7) * HS)
              + ks0 * 512 + lane * 8;
      st_b128_sc1(ho, w);
    }
    /* per-wave flag check. line0=L1, line1=L2, line2=FC (64B each).
       thresholds (entering phase p+1):
         L1: L1>=p, L2>=p-6 | L2: L1>=p, L2>=p, FC>=p-6 | FC: L2>=p
       own-block flag exempt (published concurrently by duty wave). */
    {
      int line = lane >> 2;
      int lc = (line < 3) ? line : 0;
      const int* fp = (const int*)ws + (group << 6) + (lc << 4) + ((lane & 3) << 2);
      int thr;
      if (cls == 0)      thr = (line == 0) ? p : (line == 1 ? p - 6 : THR_IGN);
      else if (cls == 1) thr = (line == 0) ? p : (line == 1 ? p : (line == 2 ? p - 6 : THR_IGN));
      else               thr = (line == 1) ? p : THR_IGN;
      if (line >= 3) thr = THR_IGN;
      const int exj = (line == cls && (lane & 3) == (owni >> 2)) ? (owni & 3) : -1;
      /* first poll doubles as store-drain (vmcnt(0) inside asm) */
      i32x4 f;
      asm volatile("global_load_dwordx4 %0, %1, off sc1\n\ts_waitcnt vmcnt(0)"
                   : "=&v"(f) : "v"(fp) : "memory");
      if (wv == duty && lane == 0)
        asm volatile("global_store_dword %0, %1, off sc1"
                     :: "v"(flagp), "v"(p) : "memory");
      /* L1: pre-gather next phase's P1 terms (in flight during poll) */
      if (cls == 0 && p < SEQn) {
        const f16* pr = P1 + (size_t)x[p * 64 + group * 16 + erow] * 2048 + j0 + eu;
#pragma unroll
        for (int g = 0; g < 4; ++g) pgf[g] = (float)pr[g * 512];
      }
      if (p < NPHASE) {
        int ok = ((f[0] >= thr) | (exj == 0)) & ((f[1] >= thr) | (exj == 1))
               & ((f[2] >= thr) | (exj == 2)) & ((f[3] >= thr) | (exj == 3));
        while (!__all(ok)) {
          __builtin_amdgcn_s_sleep(1);
          asm volatile("global_load_dwordx4 %0, %1, off sc1\n\ts_waitcnt vmcnt(0)"
                       : "=&v"(f) : "v"(fp) : "memory");
          ok = ((f[0] >= thr) | (exj == 0)) & ((f[1] >= thr) | (exj == 1))
             & ((f[2] >= thr) | (exj == 2)) & ((f[3] >= thr) | (exj == 3));
        }
      }
    }
    /* no block barrier here: waves proceed independently; part[] writes
       for p+1 are safe (all epilogue reads finished before barrier B). */
  }
}

extern "C" void kernel_launch(void* const* d_in, const int* in_sizes, int n_in,
                              void* d_out, int out_size, void* d_ws, size_t ws_size,
                              hipStream_t stream) {
  (void)in_sizes; (void)n_in; (void)out_size; (void)ws_size;
  const int*   x    = (const int*)  d_in[0];
  const float* h0   = (const float*)d_in[1];
  const float* c0   = (const float*)d_in[2];
  const float* emb  = (const float*)d_in[3];
  const float* Wih1 = (const float*)d_in[4];
  const float* Whh1 = (const float*)d_in[5];
  const float* bih1 = (const float*)d_in[6];
  const float* bhh1 = (const float*)d_in[7];
  const float* Wih2 = (const float*)d_in[8];
  const float* Whh2 = (const float*)d_in[9];
  const float* bih2 = (const float*)d_in[10];
  const float* bhh2 = (const float*)d_in[11];
  const float* Wfc  = (const float*)d_in[12];
  const float* bfc  = (const float*)d_in[13];
  char* ws = (char*)d_ws;

  hipLaunchKernelGGL(k_init, dim3(128), dim3(256), 0, stream, h0, ws);
  hipLaunchKernelGGL(k_p1,   dim3(512), dim3(256), 0, stream, emb, Wih1, bih1, bhh1, ws);
  hipLaunchKernelGGL(k_lstm, dim3(NBLK), dim3(512), 0, stream,
                     x, c0, Whh1, Wih2, Whh2, bih2, bhh2, Wfc, bfc,
                     (float*)d_out, ws);
}